// Round 1
// baseline (108.926 us; speedup 1.0000x reference)
//
#include <hip/hip_runtime.h>
#include <hip/hip_bf16.h>

#define NFFT 2048
#define K4   4096          // concatenated K (cos | -sin)
#define NCOL 2048          // B*T columns
#define TT   512
#define BB   4
#define STRIDE 512
#define OUTL 261632        // per-batch trimmed output length
#define OUTTOT (BB*OUTL)

typedef __attribute__((ext_vector_type(8))) short short8;
typedef __attribute__((ext_vector_type(4))) float f32x4;

__device__ __forceinline__ unsigned short f2bf(float x) {
    union { float f; unsigned int u; } v; v.f = x;
    unsigned int r = v.u + 0x7fffu + ((v.u >> 16) & 1u);   // RNE
    return (unsigned short)(r >> 16);
}

// ---- conv_a: Ab[n][k] = bf16([cos | -sin]), row-major [2048][4096] ----
__global__ __launch_bounds__(256) void conv_a(const float* __restrict__ kc,
                                              const float* __restrict__ ks,
                                              unsigned short* __restrict__ Ab) {
    int id = blockIdx.x * 256 + threadIdx.x;      // one thread = 2 elements
    int e = id * 2;
    if (e >= NFFT * NFFT) return;
    int n = e >> 11;
    int f = e & 2047;
    float2 c = *reinterpret_cast<const float2*>(kc + e);
    float2 s = *reinterpret_cast<const float2*>(ks + e);
    unsigned short* row = Ab + (size_t)n * K4;
    row[f]            = f2bf(c.x);
    row[f + 1]        = f2bf(c.y);
    row[2048 + f]     = f2bf(-s.x);
    row[2048 + f + 1] = f2bf(-s.y);
}

// ---- conv_b: transpose X -> Bt[c][k] bf16, c=b*512+t, k=f (real) / 2048+f (imag) ----
__global__ __launch_bounds__(256) void conv_b(const float* __restrict__ X,
                                              unsigned short* __restrict__ Bt) {
    __shared__ float ldr[64][65];
    __shared__ float ldi[64][65];
    int b  = blockIdx.z;
    int f0 = blockIdx.x * 64;
    int t0 = blockIdx.y * 64;
    int tid = threadIdx.x;
    for (int rep = 0; rep < 16; rep++) {
        int idx = rep * 256 + tid;
        int fi = idx >> 6, ti = idx & 63;
        const float* p = X + ((size_t)(b * NFFT + f0 + fi) * TT + t0 + ti) * 2;
        float2 v = *reinterpret_cast<const float2*>(p);
        ldr[fi][ti] = v.x;
        ldi[fi][ti] = v.y;
    }
    __syncthreads();
    for (int rep = 0; rep < 16; rep++) {
        int idx = rep * 256 + tid;
        int ti = idx >> 6, fi = idx & 63;
        int c = b * TT + t0 + ti;
        Bt[(size_t)c * K4 + f0 + fi]        = f2bf(ldr[fi][ti]);
        Bt[(size_t)c * K4 + 2048 + f0 + fi] = f2bf(ldi[fi][ti]);
    }
}

// ---- GEMM: Ft[c][n] = sum_k Bt[c][k] * Ab[n][k]  (frames transposed) ----
typedef const __attribute__((address_space(1))) void* gas_p;
typedef __attribute__((address_space(3))) void* las_p;

__global__ __launch_bounds__(256) void gemm_k(const unsigned short* __restrict__ Bt,
                                              const unsigned short* __restrict__ Ab,
                                              float* __restrict__ Ft) {
    __shared__ unsigned short As[128 * 64];   // c-rows, K-contiguous
    __shared__ unsigned short Bs[128 * 64];   // n-rows, K-contiguous
    int c0 = blockIdx.x * 128;
    int n0 = blockIdx.y * 128;
    int tid  = threadIdx.x;
    int lane = tid & 63;
    int wave = tid >> 6;

    f32x4 acc[4][4] = {};

    for (int k0 = 0; k0 < K4; k0 += 64) {
        __syncthreads();   // protect LDS from previous iteration's readers
        for (int i = 0; i < 4; i++) {
            int chunk = wave * 4 + i;              // 0..15, 8 rows each (1024B)
            int row = chunk * 8 + (lane >> 3);
            const unsigned short* ga = Bt + (size_t)(c0 + row) * K4 + k0 + (lane & 7) * 8;
            __builtin_amdgcn_global_load_lds((gas_p)(const void*)ga,
                                             (las_p)(void*)(As + chunk * 512), 16, 0, 0);
            const unsigned short* gb = Ab + (size_t)(n0 + row) * K4 + k0 + (lane & 7) * 8;
            __builtin_amdgcn_global_load_lds((gas_p)(const void*)gb,
                                             (las_p)(void*)(Bs + chunk * 512), 16, 0, 0);
        }
        __syncthreads();   // staging complete (compiler drains vmcnt before barrier)

        int wc = (wave >> 1) * 64;
        int wn = (wave & 1) * 64;
        for (int kk = 0; kk < 2; kk++) {
            short8 a[4], b[4];
            for (int i = 0; i < 4; i++)
                a[i] = *reinterpret_cast<const short8*>(
                    As + (wc + i * 16 + (lane & 15)) * 64 + kk * 32 + (lane >> 4) * 8);
            for (int i = 0; i < 4; i++)
                b[i] = *reinterpret_cast<const short8*>(
                    Bs + (wn + i * 16 + (lane & 15)) * 64 + kk * 32 + (lane >> 4) * 8);
            for (int i = 0; i < 4; i++)
                for (int j = 0; j < 4; j++)
                    acc[i][j] = __builtin_amdgcn_mfma_f32_16x16x32_bf16(
                        a[i], b[j], acc[i][j], 0, 0, 0);
        }
    }

    // epilogue: D[r=c][col=n], col=lane&15, row=(lane>>4)*4+reg
    int wc = (wave >> 1) * 64;
    int wn = (wave & 1) * 64;
    for (int i = 0; i < 4; i++)
        for (int j = 0; j < 4; j++) {
            int c = c0 + wc + i * 16 + (lane >> 4) * 4;
            int n = n0 + wn + j * 16 + (lane & 15);
            for (int r = 0; r < 4; r++)
                Ft[(size_t)(c + r) * NFFT + n] = acc[i][j][r];
        }
}

// ---- OLA + window sumsquare normalization + trim ----
__global__ __launch_bounds__(256) void ola_k(const float* __restrict__ Ft,
                                             const float* __restrict__ win,
                                             float* __restrict__ out) {
    int j1 = blockIdx.x * 256 + threadIdx.x;
    if (j1 >= OUTTOT) return;
    int b  = j1 / OUTL;
    int jp = j1 - b * OUTL;
    int j  = jp + 1024;             // untrimmed sample index
    int tbase = j >> 9;
    int r = j & 511;
    float acc = 0.f, ws = 0.f;
    #pragma unroll
    for (int k = 0; k < 4; k++) {
        int t = tbase - k;
        if (t >= 0 && t < TT) {
            int n = r + (k << 9);
            float w = win[n];
            acc += Ft[(size_t)(b * TT + t) * NFFT + n] * w;
            ws  += w * w;
        }
    }
    float y = acc * (1.0f / (float)NFFT);
    if (ws > 1e-10f) y /= ws;
    out[j1] = y;
}

extern "C" void kernel_launch(void* const* d_in, const int* in_sizes, int n_in,
                              void* d_out, int out_size, void* d_ws, size_t ws_size,
                              hipStream_t stream) {
    const float* X  = (const float*)d_in[0];
    const float* kc = (const float*)d_in[1];
    const float* ks = (const float*)d_in[2];
    const float* w  = (const float*)d_in[3];
    float* out = (float*)d_out;

    unsigned short* Ab = (unsigned short*)d_ws;                       // 16 MB
    unsigned short* Bt = Ab + (size_t)NFFT * K4;                      // 16 MB
    float*          Ft = (float*)(Bt + (size_t)NCOL * K4);            // 16 MB

    conv_a<<<dim3((NFFT * NFFT / 2 + 255) / 256), dim3(256), 0, stream>>>(kc, ks, Ab);
    conv_b<<<dim3(32, 8, 4), dim3(256), 0, stream>>>(X, Bt);
    gemm_k<<<dim3(16, 16), dim3(256), 0, stream>>>(Bt, Ab, Ft);
    ola_k<<<dim3((OUTTOT + 255) / 256), dim3(256), 0, stream>>>(Ft, w, out);
}

// Round 2
// 61.824 us; speedup vs baseline: 1.7619x; 1.7619x over previous
//
#include <hip/hip_runtime.h>

#define NFFT 2048
#define TT   512
#define BB   4
#define STRIDE 512
#define OUTL 261632        // per-batch trimmed output length
#define OUTTOT (BB*OUTL)

// ---- fft_k: one block per (b,t) column. Inverse-DFT (e^{+i}) via radix-2
// Stockham autosort in LDS. Writes frames_T[c][n] = Re(sum_f X e^{+2pi i nf/N}).
__global__ __launch_bounds__(256) void fft_k(const float* __restrict__ X,
                                             const float* __restrict__ kc,
                                             const float* __restrict__ ks,
                                             float* __restrict__ Ft) {
    __shared__ float b0R[2048], b0I[2048], b1R[2048], b1I[2048];
    __shared__ float tc[1024], ts[1024];   // twiddle table: e^{+2pi i m/2048}, m<1024

    const int c   = blockIdx.x;            // c = b*512 + t
    const int b   = c >> 9;
    const int t   = c & 511;
    const int tid = threadIdx.x;

    // ---- twiddle table (coalesced from kernel row n=1) ----
    #pragma unroll
    for (int r = 0; r < 4; r++) {
        int m = tid + 256 * r;
        if (m < 1024) {
            tc[m] = kc[2048 + m];
            ts[m] = ks[2048 + m];          // inverse transform: +sin
        }
    }

    // ---- stage 0 fused with global load (n=2048, s=1, m=1024) ----
    #pragma unroll
    for (int r = 0; r < 4; r++) {
        int u = tid + 256 * r;             // u = p (butterfly index), 0..1023
        const float2 xa = *reinterpret_cast<const float2*>(
            X + ((size_t)(b * NFFT + u)        * TT + t) * 2);
        const float2 xb = *reinterpret_cast<const float2*>(
            X + ((size_t)(b * NFFT + u + 1024) * TT + t) * 2);
        float wr = kc[2048 + u];           // coalesced global twiddle for stage 0
        float wi = ks[2048 + u];
        b0R[2 * u]     = xa.x + xb.x;
        b0I[2 * u]     = xa.y + xb.y;
        float dr = xa.x - xb.x;
        float di = xa.y - xb.y;
        b0R[2 * u + 1] = dr * wr - di * wi;
        b0I[2 * u + 1] = dr * wi + di * wr;
    }
    __syncthreads();

    // ---- stages 1..9: ping-pong LDS ----
    float *sR = b0R, *sI = b0I, *dR = b1R, *dI = b1I;
    for (int i = 1; i <= 9; i++) {
        const int s = 1 << i;
        #pragma unroll
        for (int r = 0; r < 4; r++) {
            int u  = tid + 256 * r;        // j1 = s*p + q = u
            int tw = u & ~(s - 1);         // twiddle index = p<<i
            int j3 = u + tw;               // dst index = 2sp + q
            float ar = sR[u],        ai = sI[u];
            float br = sR[u + 1024], bi = sI[u + 1024];
            float wr = tc[tw], wi = ts[tw];
            dR[j3] = ar + br;
            dI[j3] = ai + bi;
            float dr = ar - br;
            float di = ai - bi;
            dR[j3 + s] = dr * wr - di * wi;
            dI[j3 + s] = dr * wi + di * wr;
        }
        __syncthreads();
        float* tmp;
        tmp = sR; sR = dR; dR = tmp;
        tmp = sI; sI = dI; dI = tmp;
    }

    // ---- stage 10 fused epilogue (s=1024, m=1, w=1): only real parts needed ----
    float* out = Ft + (size_t)c * NFFT;
    #pragma unroll
    for (int r = 0; r < 4; r++) {
        int u = tid + 256 * r;
        float ar = sR[u];
        float br = sR[u + 1024];
        out[u]        = ar + br;
        out[u + 1024] = ar - br;
    }
}

// ---- OLA + window sumsquare normalization + trim ----
__global__ __launch_bounds__(256) void ola_k(const float* __restrict__ Ft,
                                             const float* __restrict__ win,
                                             float* __restrict__ out) {
    int j1 = blockIdx.x * 256 + threadIdx.x;
    if (j1 >= OUTTOT) return;
    int b  = j1 / OUTL;
    int jp = j1 - b * OUTL;
    int j  = jp + 1024;             // untrimmed sample index
    int tbase = j >> 9;
    int r = j & 511;
    float acc = 0.f, ws = 0.f;
    #pragma unroll
    for (int k = 0; k < 4; k++) {
        int t = tbase - k;
        if (t >= 0 && t < TT) {
            int n = r + (k << 9);
            float w = win[n];
            acc += Ft[(size_t)(b * TT + t) * NFFT + n] * w;
            ws  += w * w;
        }
    }
    float y = acc * (1.0f / (float)NFFT);
    if (ws > 1e-10f) y /= ws;
    out[j1] = y;
}

extern "C" void kernel_launch(void* const* d_in, const int* in_sizes, int n_in,
                              void* d_out, int out_size, void* d_ws, size_t ws_size,
                              hipStream_t stream) {
    const float* X  = (const float*)d_in[0];
    const float* kc = (const float*)d_in[1];
    const float* ks = (const float*)d_in[2];
    const float* w  = (const float*)d_in[3];
    float* out = (float*)d_out;

    float* Ft = (float*)d_ws;                     // 2048*2048 f32 = 16.8 MB

    fft_k<<<dim3(BB * TT), dim3(256), 0, stream>>>(X, kc, ks, Ft);
    ola_k<<<dim3((OUTTOT + 255) / 256), dim3(256), 0, stream>>>(Ft, w, out);
}

// Round 3
// 34.346 us; speedup vs baseline: 3.1714x; 1.8000x over previous
//
#include <hip/hip_runtime.h>

#define NFFT 2048
#define TT   512
#define BB   4
#define OUTL 261632        // per-batch trimmed output length
#define OUTTOT (BB*OUTL)

__device__ __forceinline__ float2 cmul(float2 a, float2 w) {
    return make_float2(a.x * w.x - a.y * w.y, a.x * w.y + a.y * w.x);
}

// radix-4 DIT butterfly (inverse transform, +i), twiddles w1, w1^2, w1^3
__device__ __forceinline__ void bf4(const float2 a[4], float2 o[4], float2 w1) {
    float2 w2 = make_float2(w1.x * w1.x - w1.y * w1.y, 2.f * w1.x * w1.y);
    float2 w3 = cmul(w1, w2);
    float t0r = a[0].x + a[2].x, t0i = a[0].y + a[2].y;
    float t1r = a[0].x - a[2].x, t1i = a[0].y - a[2].y;
    float t2r = a[1].x + a[3].x, t2i = a[1].y + a[3].y;
    float t3r = a[3].y - a[1].y, t3i = a[1].x - a[3].x;   // i*(a1-a3)
    o[0] = make_float2(t0r + t2r, t0i + t2i);
    o[1] = cmul(make_float2(t1r + t3r, t1i + t3i), w1);
    o[2] = cmul(make_float2(t0r - t2r, t0i - t2i), w2);
    o[3] = cmul(make_float2(t1r - t3r, t1i - t3i), w3);
}

// LDS index swizzles (round-specific, bijective involutions)
template<int SIG> __device__ __forceinline__ int sig(int x) {
    if constexpr (SIG == 0) return x;
    else if constexpr (SIG == 2) return x ^ (((x >> 5) & 3) << 2);
    else                        return x ^ (((x >> 6) & 1) << 4);
}

template<int SBITS, int SR, int SW>
__device__ __forceinline__ void midstage(float* bR, float* bI, int tid,
                                         const float* tw_c, const float* tw_s) {
    const int s = 1 << SBITS;
    float2 ra[4], rb[4];
#pragma unroll
    for (int q = 0; q < 4; q++) {
        int a1 = sig<SR>(tid + 512 * q);
        int a2 = sig<SR>(tid + 256 + 512 * q);
        ra[q] = make_float2(bR[a1], bI[a1]);
        rb[q] = make_float2(bR[a2], bI[a2]);
    }
    __syncthreads();
    const int mA = tid & ~(s - 1), rA = tid & (s - 1);
    const int mB = (tid + 256) & ~(s - 1), rB = (tid + 256) & (s - 1);
    float2 wA = make_float2(tw_c[mA], tw_s[mA]);
    float2 wB = make_float2(tw_c[mB], tw_s[mB]);
    float2 oA[4], oB[4];
    bf4(ra, oA, wA);
    bf4(rb, oB, wB);
    const int jA = 4 * mA + rA, jB = 4 * mB + rB;
#pragma unroll
    for (int k = 0; k < 4; k++) {
        int d1 = sig<SW>(jA + k * s);
        int d2 = sig<SW>(jB + k * s);
        bR[d1] = oA[k].x; bI[d1] = oA[k].y;
        bR[d2] = oB[k].x; bI[d2] = oB[k].y;
    }
    __syncthreads();
}

// One block per (b,t) column: 2048-pt inverse DFT, real parts out.
__global__ __launch_bounds__(256) void fft_k(const float* __restrict__ X,
                                             const float* __restrict__ kc,
                                             const float* __restrict__ ks,
                                             float* __restrict__ Ft) {
    __shared__ float bR[2048];
    __shared__ float bI[2048];
    const int S = blockIdx.x;
    // XCD-aware remap: XCD x owns contiguous columns [256x, 256x+256),
    // dispatch-adjacent blocks on an XCD cover consecutive t (L2 line reuse).
    const int c = ((S & 7) << 8) + (((S >> 6) & 31) << 3) + ((S >> 3) & 7);
    const int b = c >> 9;
    const int t = c & 511;
    const int tid = threadIdx.x;
    const float* tw_c = kc + 2048;    // cos(2*pi*m/2048), m = 0..2047 (row n=1)
    const float* tw_s = ks + 2048;    // +sin (inverse transform)

    // ---- stage 1 (radix-4, s=1) fused with global load ----
    const float* Xb = X + ((size_t)(b * 2048) * 512 + t) * 2;
    float2 xa[4], xb_[4];
#pragma unroll
    for (int q = 0; q < 4; q++) {
        xa[q]  = *reinterpret_cast<const float2*>(Xb + (size_t)(tid + 512 * q) * 1024);
        xb_[q] = *reinterpret_cast<const float2*>(Xb + (size_t)(tid + 256 + 512 * q) * 1024);
    }
    float2 w1a = make_float2(tw_c[tid], tw_s[tid]);
    float2 w1b = make_float2(tw_c[tid + 256], tw_s[tid + 256]);
    float2 oA[4], oB[4];
    bf4(xa, oA, w1a);
    bf4(xb_, oB, w1b);
    *reinterpret_cast<float4*>(bR + 4 * tid)         = make_float4(oA[0].x, oA[1].x, oA[2].x, oA[3].x);
    *reinterpret_cast<float4*>(bI + 4 * tid)         = make_float4(oA[0].y, oA[1].y, oA[2].y, oA[3].y);
    *reinterpret_cast<float4*>(bR + 4 * (tid + 256)) = make_float4(oB[0].x, oB[1].x, oB[2].x, oB[3].x);
    *reinterpret_cast<float4*>(bI + 4 * (tid + 256)) = make_float4(oB[0].y, oB[1].y, oB[2].y, oB[3].y);
    __syncthreads();

    // ---- mid stages s=4, 16, 64 (single-buffer read/bar/write/bar) ----
    midstage<2, 0, 2>(bR, bI, tid, tw_c, tw_s);
    midstage<4, 2, 3>(bR, bI, tid, tw_c, tw_s);
    midstage<6, 3, 0>(bR, bI, tid, tw_c, tw_s);

    // ---- fused final: radix-4 (s=256, twiddles i^(k/2)) + radix-2 (s=1024) + real epilogue ----
    float2 aA[4], aB[4];
#pragma unroll
    for (int q = 0; q < 4; q++) {
        aA[q] = make_float2(bR[tid + 512 * q],       bI[tid + 512 * q]);
        aB[q] = make_float2(bR[tid + 256 + 512 * q], bI[tid + 256 + 512 * q]);
    }
    // butterfly A (a=0): twiddles = 1; only real parts of outputs needed
    float At0r = aA[0].x + aA[2].x;
    float At1r = aA[0].x - aA[2].x;
    float At2r = aA[1].x + aA[3].x;
    float At3r = aA[3].y - aA[1].y;          // Re(i*(a1-a3))
    float PA0 = At0r + At2r;
    float PA1 = At1r + At3r;
    float PA2 = At0r - At2r;
    float PA3 = At1r - At3r;
    // butterfly B (a=1): twiddles W^{256k} = e^{+i pi k/4}
    float Bt0r = aB[0].x + aB[2].x, Bt0i = aB[0].y + aB[2].y;
    float Bt1r = aB[0].x - aB[2].x, Bt1i = aB[0].y - aB[2].y;
    float Bt2r = aB[1].x + aB[3].x, Bt2i = aB[1].y + aB[3].y;
    float Bt3r = aB[3].y - aB[1].y, Bt3i = aB[1].x - aB[3].x;
    const float h = 0.70710678118654752f;
    float PB0 = Bt0r + Bt2r;
    float u1r = Bt1r + Bt3r, u1i = Bt1i + Bt3i;
    float PB1 = h * (u1r - u1i);             // Re((h+ih)*u1)
    float PB2 = -(Bt0i - Bt2i);              // Re(i*(t0-t2))
    float u3r = Bt1r - Bt3r, u3i = Bt1i - Bt3i;
    float PB3 = -h * (u3r + u3i);            // Re((-h+ih)*u3)

    float* outp = Ft + (size_t)c * 2048 + tid;
    outp[0]    = PA0 + PB0;
    outp[256]  = PA1 + PB1;
    outp[512]  = PA2 + PB2;
    outp[768]  = PA3 + PB3;
    outp[1024] = PA0 - PB0;
    outp[1280] = PA1 - PB1;
    outp[1536] = PA2 - PB2;
    outp[1792] = PA3 - PB3;
}

// ---- OLA + window sumsquare normalization + trim ----
__global__ __launch_bounds__(256) void ola_k(const float* __restrict__ Ft,
                                             const float* __restrict__ win,
                                             float* __restrict__ out) {
    int j1 = blockIdx.x * 256 + threadIdx.x;
    if (j1 >= OUTTOT) return;
    int b  = j1 / OUTL;
    int jp = j1 - b * OUTL;
    int j  = jp + 1024;             // untrimmed sample index
    int tbase = j >> 9;
    int r = j & 511;
    float acc = 0.f, ws = 0.f;
    #pragma unroll
    for (int k = 0; k < 4; k++) {
        int t = tbase - k;
        if (t >= 0 && t < TT) {
            int n = r + (k << 9);
            float w = win[n];
            acc += Ft[(size_t)(b * TT + t) * NFFT + n] * w;
            ws  += w * w;
        }
    }
    float y = acc * (1.0f / (float)NFFT);
    if (ws > 1e-10f) y /= ws;
    out[j1] = y;
}

extern "C" void kernel_launch(void* const* d_in, const int* in_sizes, int n_in,
                              void* d_out, int out_size, void* d_ws, size_t ws_size,
                              hipStream_t stream) {
    const float* X  = (const float*)d_in[0];
    const float* kc = (const float*)d_in[1];
    const float* ks = (const float*)d_in[2];
    const float* w  = (const float*)d_in[3];
    float* out = (float*)d_out;

    float* Ft = (float*)d_ws;                     // 2048*2048 f32 = 16.8 MB

    fft_k<<<dim3(BB * TT), dim3(256), 0, stream>>>(X, kc, ks, Ft);
    ola_k<<<dim3((OUTTOT + 255) / 256), dim3(256), 0, stream>>>(Ft, w, out);
}